// Round 5
// baseline (144.320 us; speedup 1.0000x reference)
//
#include <hip/hip_runtime.h>
#include <hip/hip_bf16.h>

// CrossAttention: B=4, C=256, H=W=64 -> N=M=4096, RC=32
// v12: attn LDS-pressure fix via m-group split.
//  - 8 waves = 2 groups x 4. Group g owns m-half [g*2048, g*2048+2048):
//    own P ping-pong buffer, 32 iters of 64m. Within a group each wave
//    does a QK quarter (t = wg&1 n-tile, h = wg>>1 m-32-half): 2 MFMA +
//    8 exp, AND PV for d-slice [wg*64, wg*64+64): 2 scaled 32x32x64 MFMAs.
//  - P-read amplification halves (4 readers/tile, was 8): LDS pipe per
//    64m of work ~960 -> ~290 cyc. Barriers halve (32/block). All waves
//    have identical per-iter work (no barrier straggler).
//  - Cross-group O combine at end via LDS (bf16), l via l_sh[4][32].
//  - counted barrier (lgkmcnt only) keeps V/K global loads in flight.

#define B_ 4
#define C_ 256
#define N_ 4096
#define M_ 4096
#define SCALE_ 0.17677669529663687f  // 1/sqrt(32)

typedef __bf16 bf16x8 __attribute__((ext_vector_type(8)));
typedef float f32x4 __attribute__((ext_vector_type(4)));
typedef float f32x16 __attribute__((ext_vector_type(16)));
typedef int i32x8 __attribute__((ext_vector_type(8)));

#define AS1 __attribute__((address_space(1)))
#define AS3 __attribute__((address_space(3)))

static __device__ __forceinline__ unsigned short f2bf(float f) {
    unsigned int u = __float_as_uint(f);
    return (unsigned short)((u + 0x7fffu + ((u >> 16) & 1u)) >> 16);
}
static __device__ __forceinline__ unsigned bfpk(float a, float b) {
    return (unsigned)f2bf(a) | ((unsigned)f2bf(b) << 16);
}
// LDS-ordering barrier that does NOT drain vmcnt.
static __device__ __forceinline__ void p_barrier() {
    asm volatile("s_waitcnt lgkmcnt(0)" ::: "memory");
    __builtin_amdgcn_s_barrier();
    asm volatile("" ::: "memory");
}

// ---------------------------------------------------------------------------
// prep: weights -> bf16 MFMA fragment order. grid 40 x 256. (unchanged)
// ---------------------------------------------------------------------------
__global__ __launch_bounds__(256) void prep(
        const float* __restrict__ Wq, const float* __restrict__ Wk,
        const float* __restrict__ Wv, uint4* __restrict__ Wqf,
        uint4* __restrict__ Wkf, uint4* __restrict__ Wvf) {
    int bid = blockIdx.x, t = threadIdx.x;
    const float* W;
    uint4* dst;
    int frag;
    if (bid < 32)      { W = Wv; dst = Wvf; frag = (bid * 256 + t) >> 6; }
    else if (bid < 36) { W = Wq; dst = Wqf; frag = ((bid - 32) * 256 + t) >> 6; }
    else               { W = Wk; dst = Wkf; frag = ((bid - 36) * 256 + t) >> 6; }
    int lane = t & 63, low = lane & 15, q = lane >> 4;
    int fch = frag & 7, fr = frag >> 3;
    const float* wp = W + (size_t)(fr * 16 + low) * C_ + fch * 32 + q * 8;
    float4 w0 = *(const float4*)wp;
    float4 w1 = *(const float4*)(wp + 4);
    uint4 pk = {bfpk(w0.x, w0.y), bfpk(w0.z, w0.w),
                bfpk(w1.x, w1.y), bfpk(w1.z, w1.w)};
    dst[(size_t)frag * 64 + lane] = pk;
}

// ---------------------------------------------------------------------------
// Fused transpose + projections. grid 512 x 256. (unchanged from v6)
// ---------------------------------------------------------------------------
__global__ __launch_bounds__(256, 2) void fused_proj(
        const float* __restrict__ x, const float* __restrict__ ctx,
        const uint4* __restrict__ Wqf, const uint4* __restrict__ Wkf,
        const uint4* __restrict__ Wvf,
        const float* __restrict__ bq, const float* __restrict__ bk,
        const float* __restrict__ bv,
        unsigned short* __restrict__ Qf, unsigned short* __restrict__ Kf,
        unsigned char* __restrict__ Vf) {
    __shared__ unsigned short X[64][264];
    __shared__ unsigned short Pl[4][16 * 40];
    __shared__ unsigned char  Vw[4][16 * 40];

    int bid = blockIdx.x;
    bool isX = bid >= 256;
    int lb = bid & 255;
    int b = lb >> 6, pt64 = lb & 63;
    const float* __restrict__ in = (isX ? x : ctx) + (size_t)b * C_ * N_ + pt64 * 64;
    int t = threadIdx.x, wg = t >> 6, lane = t & 63;
    int low = lane & 15, q = lane >> 4;

    {
        int pL = lane;
        const float* s0 = in + pL;
#pragma unroll
        for (int ct = 0; ct < 4; ct++) {
            const float* s2 = s0 + (size_t)(ct * 64 + wg * 16) * N_;
            float v[16];
#pragma unroll
            for (int k = 0; k < 16; k++) v[k] = s2[(size_t)k * N_];
#pragma unroll
            for (int k = 0; k < 16; k += 2)
                *(unsigned*)&X[pL][ct * 64 + wg * 16 + k] = bfpk(v[k], v[k + 1]);
        }
    }
    __syncthreads();

    {
        const uint4* __restrict__ Wf = isX ? Wqf : Wkf;
        const float* __restrict__ bias = isX ? bq : bk;
        unsigned short* __restrict__ dst = isX ? Qf : Kf;
        bf16x8 xf[8];
#pragma unroll
        for (int ch = 0; ch < 8; ch++)
            xf[ch] = *(const bf16x8*)&X[wg * 16 + low][ch * 32 + q * 8];
        const f32x4 zero = {0.f, 0.f, 0.f, 0.f};
        f32x4 acc[2] = {zero, zero};
#pragma unroll
        for (int rt = 0; rt < 2; rt++)
#pragma unroll
            for (int ch = 0; ch < 8; ch++) {
                uint4 wv = Wf[(rt * 8 + ch) * 64 + lane];
                acc[rt] = __builtin_amdgcn_mfma_f32_16x16x32_bf16(
                    __builtin_bit_cast(bf16x8, wv), xf[ch], acc[rt], 0, 0, 0);
            }
        unsigned short* Pw = &Pl[wg][0];
#pragma unroll
        for (int rt = 0; rt < 2; rt++) {
            float b0 = bias[rt * 16 + q * 4 + 0], b1 = bias[rt * 16 + q * 4 + 1];
            float b2 = bias[rt * 16 + q * 4 + 2], b3 = bias[rt * 16 + q * 4 + 3];
            uint2 pk = {bfpk(acc[rt][0] + b0, acc[rt][1] + b1),
                        bfpk(acc[rt][2] + b2, acc[rt][3] + b3)};
            *(uint2*)(Pw + low * 40 + rt * 16 + q * 4) = pk;
        }
        uint4 frag = *(const uint4*)(Pw + low * 40 + q * 8);
        ((uint4*)dst)[((size_t)b * 256 + pt64 * 4 + wg) * 64 + lane] = frag;
    }

    if (!isX) {
        int mstep = wg >> 1, dh = wg & 1;
        bf16x8 vfr[2][8];
#pragma unroll
        for (int mt = 0; mt < 2; mt++)
#pragma unroll
            for (int ch = 0; ch < 8; ch++)
                vfr[mt][ch] = *(const bf16x8*)&X[mstep * 32 + mt * 16 + low][ch * 32 + q * 8];
        unsigned char* Vv = &Vw[wg][0];
        int msg = pt64 * 2 + mstep;
        const f32x4 zero = {0.f, 0.f, 0.f, 0.f};
#pragma unroll
        for (int dt8 = 0; dt8 < 8; dt8++) {
            int dt = dh * 8 + dt8;
            f32x4 a0 = zero, a1 = zero;
#pragma unroll
            for (int ch = 0; ch < 8; ch++) {
                uint4 wv = Wvf[(dt * 8 + ch) * 64 + lane];
                bf16x8 wfr = __builtin_bit_cast(bf16x8, wv);
                a0 = __builtin_amdgcn_mfma_f32_16x16x32_bf16(vfr[0][ch], wfr, a0, 0, 0, 0);
                a1 = __builtin_amdgcn_mfma_f32_16x16x32_bf16(vfr[1][ch], wfr, a1, 0, 0, 0);
            }
            float bb = bv[dt * 16 + low];
            unsigned w0 = __builtin_amdgcn_cvt_pk_fp8_f32(a0[0] + bb, a0[1] + bb, 0, false);
            w0 = __builtin_amdgcn_cvt_pk_fp8_f32(a0[2] + bb, a0[3] + bb, w0, true);
            unsigned w1 = __builtin_amdgcn_cvt_pk_fp8_f32(a1[0] + bb, a1[1] + bb, 0, false);
            w1 = __builtin_amdgcn_cvt_pk_fp8_f32(a1[2] + bb, a1[3] + bb, w1, true);
            *(unsigned*)(Vv + low * 40 + q * 4) = w0;
            *(unsigned*)(Vv + low * 40 + 16 + q * 4) = w1;
            uint2 fr = *(const uint2*)(Vv + low * 40 + q * 8);
            ((uint2*)Vf)[(((size_t)b * 128 + msg) * 16 + dt) * 64 + lane] = fr;
        }
    }
}

// ---------------------------------------------------------------------------
// Flash attention v12. grid 512 x 512 (2 blocks/CU, 8 waves each).
// Block = (b, ng): 32 n rows (2 q-tiles), all 4096 m split into 2 groups.
// Wave = (g = w>>2, wg = w&3). Group g: m in [g*2048, g*2048+2048),
// 32 slabs of 64 m, own P ping-pong. Per wave per iter:
//   QK quarter (t = wg&1, h = wg>>1): 2 x mfma 16x16x32 bf16 + 8 exp +
//   pack + 2 ds_write (P for next slab)
//   PV d-slice [wg*64, wg*64+64): 2 x mfma_scale 32x32x64 f8f6f4.
// End: l_sh[4][32] sum; cross-group O add via LDS bf16; fused epilogue
// out = gamma*O/l + x.
// ---------------------------------------------------------------------------
__global__ __launch_bounds__(512, 4) void attn(
        const unsigned short* __restrict__ Qf, const unsigned short* __restrict__ Kf,
        const unsigned char* __restrict__ Vf, const float* __restrict__ x,
        const float* __restrict__ gamma, float* __restrict__ out) {
    __shared__ __align__(16) unsigned char Pb[2][2][2 * 16 * 80]; // [grp][buf] 10240 B
    __shared__ float l_sh[4][32];
    __shared__ unsigned Obuf[32 * 129];                           // 16512 B
    __shared__ unsigned Ot[32 * 129];                             // 16512 B

    // bijective swizzle: XCD pair {2b,2b+1} hosts all 128 blocks of b ->
    // per-XCD K+V working set ~1.5 MB (L2-resident).
    int bid = blockIdx.x;
    int xcd = bid & 7;
    int b = xcd >> 1;
    int ng = ((xcd & 1) << 6) | (bid >> 3);  // 0..127; n0 = ng*32

    int wave = threadIdx.x >> 6, lane = threadIdx.x & 63;
    int g = wave >> 2, wg = wave & 3;
    int q = lane >> 4, low = lane & 15;
    int hi = lane >> 5;                      // m-32-half selector (PV frags)
    int dsel = q & 1;                        // tile-parity selector
    int l31 = lane & 31;
    int t = wg & 1;                          // QK n-16-tile
    int h = wg >> 1;                         // QK m-32-half within slab

    const uint4* Qp = (const uint4*)Qf;
    const uint4* Kp = (const uint4*)Kf + (size_t)b * 256 * 64;
    const uint2* Vq = (const uint2*)(Vf + (size_t)b * 1048576) + (size_t)hi * 1024 + low;
    int slab0 = g * 32;

    bf16x8 qa = __builtin_bit_cast(bf16x8, Qp[(size_t)(b * 256 + ng * 2 + t) * 64 + lane]);

    f32x16 acc2[2];                          // [dg]: O^T 32n x 32d, d = wg*64+dg*32
    acc2[0] = (f32x16)(0.f);
    acc2[1] = (f32x16)(0.f);
    float lacc = 0.f;
    const f32x4 zero = {0.f, 0.f, 0.f, 0.f};

    unsigned char* PbG = &Pb[g][0][0];       // group's ping-pong base (2 x 2560)

    // ---- prologue: P(slab0) pack, kv <- K(slab0+1), vf <- V(slab0) ----
    uint4 kv[2];
    f32x4 s[2];
    {
#pragma unroll
        for (int u = 0; u < 2; u++)
            kv[u] = Kp[(size_t)(slab0 * 4 + h * 2 + u) * 64 + lane];
#pragma unroll
        for (int u = 0; u < 2; u++)
            s[u] = __builtin_amdgcn_mfma_f32_16x16x32_bf16(
                __builtin_bit_cast(bf16x8, kv[u]), qa, zero, 0, 0, 0);
#pragma unroll
        for (int u = 0; u < 2; u++)
            kv[u] = Kp[(size_t)((slab0 + 1) * 4 + h * 2 + u) * 64 + lane];
        unsigned char* Pw = PbG;             // buf 0
#pragma unroll
        for (int u = 0; u < 2; u++) {
            float p0 = __expf(s[u][0] * SCALE_), p1 = __expf(s[u][1] * SCALE_);
            float p2 = __expf(s[u][2] * SCALE_), p3 = __expf(s[u][3] * SCALE_);
            lacc += p0 + p1 + p2 + p3;
            unsigned w = __builtin_amdgcn_cvt_pk_fp8_f32(p0, p1, 0, false);
            w = __builtin_amdgcn_cvt_pk_fp8_f32(p2, p3, w, true);
            *(unsigned*)(Pw + t * 1280 + low * 80 + h * 32 + u * 16 + q * 4) = w;
        }
    }
    i32x8 vf[2];
#pragma unroll
    for (int dg = 0; dg < 2; dg++) {
        int dt = wg * 4 + dg * 2 + dsel;
        const uint2* Vs = Vq + (size_t)slab0 * 2048 + dt * 64;
        long* dqw = (long*)&vf[dg];
#pragma unroll
        for (int ss = 0; ss < 4; ss++)
            dqw[ss] = *(const long*)(Vs + ss * 16);
    }
    p_barrier();

    // ---- main loop: 32 slabs of 64 m per group ----
    for (int i = 0; i < 32; i++) {
        int cur = i & 1, nxt = cur ^ 1;
        bool hn = (i + 1 < 32);

        // QK for slab i+1 (kv preloaded); refill kv for slab i+2
        if (hn) {
#pragma unroll
            for (int u = 0; u < 2; u++)
                s[u] = __builtin_amdgcn_mfma_f32_16x16x32_bf16(
                    __builtin_bit_cast(bf16x8, kv[u]), qa, zero, 0, 0, 0);
            if (i + 2 < 32) {
#pragma unroll
                for (int u = 0; u < 2; u++)
                    kv[u] = Kp[(size_t)((slab0 + i + 2) * 4 + h * 2 + u) * 64 + lane];
            }
        }

        // PV(slab i): acc2[dg] += V^T P^T (32x32x64, unit scales)
        {
            const unsigned char* pr = PbG + cur * 2560 + dsel * 1280 + low * 80 + hi * 32;
            i32x8 pf;
            ((uint4*)&pf)[0] = *(const uint4*)pr;
            ((uint4*)&pf)[1] = *(const uint4*)(pr + 16);
#pragma unroll
            for (int dg = 0; dg < 2; dg++)
                acc2[dg] = __builtin_amdgcn_mfma_scale_f32_32x32x64_f8f6f4(
                    vf[dg], pf, acc2[dg], 0, 0, 0, 127, 0, 127);
        }

        // refill vf for slab i+1 (regs free after the MFMAs)
        if (hn) {
#pragma unroll
            for (int dg = 0; dg < 2; dg++) {
                int dt = wg * 4 + dg * 2 + dsel;
                const uint2* Vs = Vq + (size_t)(slab0 + i + 1) * 2048 + dt * 64;
                long* dqw = (long*)&vf[dg];
#pragma unroll
                for (int ss = 0; ss < 4; ss++)
                    dqw[ss] = *(const long*)(Vs + ss * 16);
            }
        }

        // pack P(slab i+1) into the other buffer
        if (hn) {
            unsigned char* Pw = PbG + nxt * 2560;
#pragma unroll
            for (int u = 0; u < 2; u++) {
                float p0 = __expf(s[u][0] * SCALE_), p1 = __expf(s[u][1] * SCALE_);
                float p2 = __expf(s[u][2] * SCALE_), p3 = __expf(s[u][3] * SCALE_);
                lacc += p0 + p1 + p2 + p3;
                unsigned w = __builtin_amdgcn_cvt_pk_fp8_f32(p0, p1, 0, false);
                w = __builtin_amdgcn_cvt_pk_fp8_f32(p2, p3, w, true);
                *(unsigned*)(Pw + t * 1280 + low * 80 + h * 32 + u * 16 + q * 4) = w;
            }
        }
        p_barrier();
    }

    // ---- l partials: per (group, h) -> l_sh[g*2+h][n] ----
    lacc += __shfl_xor(lacc, 16, 64);
    lacc += __shfl_xor(lacc, 32, 64);
    if (lane < 16)
        l_sh[g * 2 + h][t * 16 + low] = lacc;

    // ---- cross-group O combine via LDS (bf16 pairs) ----
    // C layout: n = lane&31, d = wg*64 + dg*32 + (r&3) + 8*(r>>2) + 4*hi.
    if (g == 1) {
#pragma unroll
        for (int dg = 0; dg < 2; dg++)
#pragma unroll
            for (int k = 0; k < 8; k++) {
                int col16 = wg * 32 + dg * 16 + (k & 1) + 4 * (k >> 1) + 2 * hi;
                Obuf[l31 * 129 + col16] = bfpk(acc2[dg][2 * k], acc2[dg][2 * k + 1]);
            }
    }
    __syncthreads();
    if (g == 0) {
#pragma unroll
        for (int dg = 0; dg < 2; dg++)
#pragma unroll
            for (int k = 0; k < 8; k++) {
                int col16 = wg * 32 + dg * 16 + (k & 1) + 4 * (k >> 1) + 2 * hi;
                unsigned pk = Obuf[l31 * 129 + col16];
                float a = acc2[dg][2 * k]     + __uint_as_float(pk << 16);
                float c = acc2[dg][2 * k + 1] + __uint_as_float(pk & 0xffff0000u);
                Ot[l31 * 129 + col16] = bfpk(a, c);
            }
    }
    __syncthreads();

    // ---- out[b][d][n0+l31] = gamma * O/l + x (8 waves, d-slice wave*32) ----
    {
        float gm = gamma[0];
        float rinv = gm / (l_sh[0][l31] + l_sh[1][l31] + l_sh[2][l31] + l_sh[3][l31]);
        int dh = hi;
        size_t nb = ((size_t)(b * 256 + wave * 32 + dh * 16)) * 4096
                    + (size_t)ng * 32 + l31;
#pragma unroll 4
        for (int j = 0; j < 16; j++) {
            unsigned pk = Ot[l31 * 129 + wave * 16 + dh * 8 + (j >> 1)];
            unsigned bits = (j & 1) ? (pk & 0xffff0000u) : (pk << 16);
            float o = __uint_as_float(bits);
            size_t idx = nb + (size_t)j * 4096;
            out[idx] = o * rinv + x[idx];
        }
    }
}

// ---------------------------------------------------------------------------
extern "C" void kernel_launch(void* const* d_in, const int* in_sizes, int n_in,
                              void* d_out, int out_size, void* d_ws, size_t ws_size,
                              hipStream_t stream) {
    const float* x     = (const float*)d_in[0];
    const float* ctx   = (const float*)d_in[1];
    const float* Wq    = (const float*)d_in[2];
    const float* bq    = (const float*)d_in[3];
    const float* Wk    = (const float*)d_in[4];
    const float* bk    = (const float*)d_in[5];
    const float* Wv    = (const float*)d_in[6];
    const float* bv    = (const float*)d_in[7];
    const float* gamma = (const float*)d_in[8];
    float* out = (float*)d_out;

    // ws: Qf 1M | Kf 1M | Vf 4.2M | Wqf/Wkf 16K | Wvf 128K
    unsigned short* Qf = (unsigned short*)d_ws;
    unsigned short* Kf = Qf + (size_t)B_ * N_ * 32;
    unsigned char*  Vf = (unsigned char*)(Kf + (size_t)B_ * M_ * 32);
    uint4* Wqf = (uint4*)(Vf + (size_t)B_ * M_ * C_);
    uint4* Wkf = Wqf + 16 * 64;
    uint4* Wvf = Wkf + 16 * 64;

    prep<<<40, 256, 0, stream>>>(Wq, Wk, Wv, Wqf, Wkf, Wvf);
    fused_proj<<<512, 256, 0, stream>>>(x, ctx, Wqf, Wkf, Wvf, bq, bk, bv, Qf, Kf, Vf);
    attn<<<512, 512, 0, stream>>>(Qf, Kf, Vf, x, gamma, out);
}